// Round 5
// baseline (839.290 us; speedup 1.0000x reference)
//
#include <hip/hip_runtime.h>
#include <math.h>

#define HD 64

__device__ __forceinline__ float silu_f(float x) {
    return x / (1.0f + __expf(-x));
}

// ---------------- node_pre: normalize, decompose, Wt0/1/2 -> Tn[n][10][64] --
__global__ __launch_bounds__(64) void node_pre(
    const float* __restrict__ X,
    const float* __restrict__ Wt0, const float* __restrict__ Wt1, const float* __restrict__ Wt2,
    float* __restrict__ Tn)
{
    int n = blockIdx.x;
    int h = threadIdx.x;
    const float* Xb = X + (size_t)n * 9 * HD + h;
    float x[9];
    float nrm = 0.f;
#pragma unroll
    for (int i = 0; i < 9; ++i) { x[i] = Xb[i * HD]; nrm += x[i] * x[i]; }
    float inv = 1.0f / (nrm + 1.0f);
#pragma unroll
    for (int i = 0; i < 9; ++i) x[i] *= inv;

    float I0 = (x[0] + x[4] + x[8]) * (1.0f / 3.0f);
    __shared__ float comp[10][HD];
    comp[0][h] = I0;
    comp[1][h] = 0.5f * (x[1] - x[3]);
    comp[2][h] = 0.5f * (x[2] - x[6]);
    comp[3][h] = 0.5f * (x[5] - x[7]);
    comp[4][h] = x[0] - I0;
    comp[5][h] = 0.5f * (x[1] + x[3]);
    comp[6][h] = 0.5f * (x[2] + x[6]);
    comp[7][h] = x[4] - I0;
    comp[8][h] = 0.5f * (x[5] + x[7]);
    comp[9][h] = x[8] - I0;
    __syncthreads();
    float acc[10];
#pragma unroll
    for (int i = 0; i < 10; ++i) acc[i] = 0.f;
    for (int k = 0; k < HD; ++k) {
        float w0 = Wt0[k * HD + h];
        float w1 = Wt1[k * HD + h];
        float w2 = Wt2[k * HD + h];
        acc[0] += comp[0][k] * w0;
        acc[1] += comp[1][k] * w1;
        acc[2] += comp[2][k] * w1;
        acc[3] += comp[3][k] * w1;
#pragma unroll
        for (int j = 0; j < 6; ++j) acc[4 + j] += comp[4 + j][k] * w2;
    }
    float* tp = Tn + (size_t)n * 640 + h;
#pragma unroll
    for (int i = 0; i < 10; ++i) tp[i * 64] = acc[i];
}

// ---------------- CSR build --------------------------------------------------
__global__ __launch_bounds__(256) void count_kernel(
    const int* __restrict__ edge_index, int* __restrict__ cnt, int E)
{
    int e = blockIdx.x * 256 + threadIdx.x;
    if (e < E) atomicAdd(&cnt[edge_index[e]], 1);
}

// 1024 threads = 16 waves; shuffle wave-scan + tiny serial cross-wave scan.
__global__ __launch_bounds__(1024) void scan_kernel(
    const int* __restrict__ cnt, int* __restrict__ offs, int* __restrict__ curs, int N)
{
    __shared__ int partials[16];
    __shared__ int base_s;
    int tid = threadIdx.x, wid = tid >> 6, lane = tid & 63;
    if (tid == 0) base_s = 0;
    __syncthreads();
    for (int start = 0; start < N; start += 1024) {
        int i = start + tid;
        int v = (i < N) ? cnt[i] : 0;
        int s = v;
#pragma unroll
        for (int d = 1; d < 64; d <<= 1) {
            int t = __shfl_up(s, d, 64);
            if (lane >= d) s += t;
        }
        if (lane == 63) partials[wid] = s;
        __syncthreads();
        if (tid == 0) {
            int run = base_s;
#pragma unroll
            for (int w = 0; w < 16; ++w) { int t = partials[w]; partials[w] = run; run += t; }
            base_s = run;
        }
        __syncthreads();
        int excl = partials[wid] + s - v;
        if (i < N) { offs[i] = excl; curs[i] = excl; }
        __syncthreads();
    }
    if (tid == 0) offs[N] = base_s;
}

// place: rank[e] = CSR slot of edge e; colP[slot] = source node of edge e.
__global__ __launch_bounds__(256) void place_kernel(
    const int* __restrict__ edge_index, int* __restrict__ curs,
    int* __restrict__ rank, int* __restrict__ colP, int E)
{
    int e = blockIdx.x * 256 + threadIdx.x;
    if (e < E) {
        int p = atomicAdd(&curs[edge_index[e]], 1);
        rank[e] = p;
        colP[p] = edge_index[E + e];
    }
}

// ---------------- MLP layers 1+2: 4 waves, lane = edge, LDS round-trip -------
// l1: wave wv computes h1 outputs [16wv,16wv+16); l2: h2 outputs [32wv,32wv+32).
// h2 written to buf row rank[e] (CSR-permuted) so downstream reads are linear.
__global__ __launch_bounds__(256, 4) void mlp_l12(
    const float* __restrict__ edge_attr, const float* __restrict__ charges,
    const float* __restrict__ edge_weight, const int* __restrict__ edge_index,
    const float* __restrict__ Ws1, const float* __restrict__ bs1,
    const float* __restrict__ Ws2, const float* __restrict__ bs2,
    const int* __restrict__ rank,
    float* __restrict__ buf, float* __restrict__ cvP, int E)
{
    __shared__ float ins[64][49];
    __shared__ float h1s[64][65];
    __shared__ int rankS[64];
    int tid = threadIdx.x;
    int wv = tid >> 6, lane = tid & 63;
    int ebase = blockIdx.x * 64;

    // stage inputs: 64 edges x 12 float4 = 768; 3 per thread
#pragma unroll
    for (int it = 0; it < 3; ++it) {
        int i = tid + it * 256;
        int e_l = i / 12, f = i % 12;
        int e = ebase + e_l;
        int ee = (e < E) ? e : (E - 1);
        float4 v;
        if (f < 8) {
            v = *(const float4*)(edge_attr + (size_t)ee * 32 + f * 4);
        } else if (f < 10) {
            int r = edge_index[ee];
            v = *(const float4*)(charges + (size_t)r * 8 + (f - 8) * 4);
        } else {
            int c = edge_index[E + ee];
            v = *(const float4*)(charges + (size_t)c * 8 + (f - 10) * 4);
        }
        ins[e_l][f * 4 + 0] = v.x; ins[e_l][f * 4 + 1] = v.y;
        ins[e_l][f * 4 + 2] = v.z; ins[e_l][f * 4 + 3] = v.w;
    }
    if (tid < 64) {
        int e = ebase + tid;
        bool valid = (e < E);
        int ee = valid ? e : (E - 1);
        int rk = valid ? rank[ee] : 0;
        rankS[tid] = rk;
        float wgt = edge_weight[ee];
        float cv = 0.5f * (__cosf(wgt * 0.6283185307179586f) + 1.0f);
        cv = (wgt < 5.0f) ? cv : 0.0f;
        if (valid) cvP[rk] = cv;
    }
    __syncthreads();

    // ---- layer 1: 48 -> 64, 16 outputs per wave ----
    {
        float a1[16];
#pragma unroll
        for (int j = 0; j < 16; j += 4) {
            float4 b = *(const float4*)(bs1 + wv * 16 + j);
            a1[j] = b.x; a1[j + 1] = b.y; a1[j + 2] = b.z; a1[j + 3] = b.w;
        }
        for (int k = 0; k < 48; ++k) {
            float xk = ins[lane][k];
#pragma unroll
            for (int j = 0; j < 16; j += 4) {
                float4 w = *(const float4*)(Ws1 + k * 64 + wv * 16 + j);
                a1[j]     += xk * w.x;
                a1[j + 1] += xk * w.y;
                a1[j + 2] += xk * w.z;
                a1[j + 3] += xk * w.w;
            }
        }
#pragma unroll
        for (int j = 0; j < 16; ++j) h1s[lane][wv * 16 + j] = silu_f(a1[j]);
    }
    __syncthreads();

    // ---- layer 2: 64 -> 128, 32 outputs per wave ----
    {
        float a2[32];
#pragma unroll
        for (int j = 0; j < 32; j += 4) {
            float4 b = *(const float4*)(bs2 + wv * 32 + j);
            a2[j] = b.x; a2[j + 1] = b.y; a2[j + 2] = b.z; a2[j + 3] = b.w;
        }
        for (int k = 0; k < 64; ++k) {
            float xk = h1s[lane][k];
#pragma unroll
            for (int j = 0; j < 32; j += 4) {
                float4 w = *(const float4*)(Ws2 + k * 128 + wv * 32 + j);
                a2[j]     += xk * w.x;
                a2[j + 1] += xk * w.y;
                a2[j + 2] += xk * w.z;
                a2[j + 3] += xk * w.w;
            }
        }
        if (ebase + lane < E) {
            float* op = buf + (size_t)rankS[lane] * 192 + wv * 32;
#pragma unroll
            for (int j = 0; j < 32; j += 4) {
                float4 o;
                o.x = silu_f(a2[j]);     o.y = silu_f(a2[j + 1]);
                o.z = silu_f(a2[j + 2]); o.w = silu_f(a2[j + 3]);
                *(float4*)(op + j) = o;
            }
        }
    }
}

// ---------------- MLP layer 3: 3 waves, LDS h2 tile, 64 outputs per wave -----
// Rows are CSR slots (contiguous). h2 staged once; in-place overwrite is safe
// after the barrier. acc[64] -> VGPR<=128 (launch_bounds(192,4)).
__global__ __launch_bounds__(192, 4) void mlp_l3(
    const float* __restrict__ Ws3, const float* __restrict__ bs3,
    const float* __restrict__ cvP, float* __restrict__ buf, int E)
{
    __shared__ float h2s[64][129];
    int tid = threadIdx.x;
    int base = blockIdx.x * 64;

    // stage 64 rows x 128 floats = 2048 float4
    for (int i = tid; i < 64 * 32; i += 192) {
        int r = i >> 5, c4 = (i & 31) << 2;
        int p = base + r;
        float4 v = make_float4(0.f, 0.f, 0.f, 0.f);
        if (p < E) v = *(const float4*)(buf + (size_t)p * 192 + c4);
        h2s[r][c4] = v.x; h2s[r][c4 + 1] = v.y; h2s[r][c4 + 2] = v.z; h2s[r][c4 + 3] = v.w;
    }
    __syncthreads();

    int wv = tid >> 6, lane = tid & 63;
    int p = base + lane;
    float cv = (p < E) ? cvP[p] : 0.f;

    float acc[64];
#pragma unroll
    for (int j = 0; j < 64; j += 4) {
        float4 b = *(const float4*)(bs3 + wv * 64 + j);
        acc[j] = b.x; acc[j + 1] = b.y; acc[j + 2] = b.z; acc[j + 3] = b.w;
    }
    for (int k = 0; k < 128; ++k) {
        float xk = h2s[lane][k];
#pragma unroll
        for (int j = 0; j < 64; j += 4) {
            float4 w = *(const float4*)(Ws3 + k * 192 + wv * 64 + j);
            acc[j]     += xk * w.x;
            acc[j + 1] += xk * w.y;
            acc[j + 2] += xk * w.z;
            acc[j + 3] += xk * w.w;
        }
    }
    if (p < E) {
        float* op = buf + (size_t)p * 192 + wv * 64;
#pragma unroll
        for (int j = 0; j < 64; j += 4) {
            float4 o;
            o.x = silu_f(acc[j]) * cv;     o.y = silu_f(acc[j + 1]) * cv;
            o.z = silu_f(acc[j + 2]) * cv; o.w = silu_f(acc[j + 3]) * cv;
            *(float4*)(op + j) = o;
        }
    }
}

// ---------------- msg kernel: sequential w stream + Tn gather ----------------
__global__ __launch_bounds__(64) void msg_kernel(
    const float* __restrict__ buf, const int* __restrict__ colP,
    const int* __restrict__ offs, const float* __restrict__ Tn,
    float* __restrict__ Mn)
{
    int n = blockIdx.x;
    int lane = threadIdx.x;
    int beg = offs[n], end = offs[n + 1];
    float a0 = 0.f, a1 = 0.f, a2 = 0.f, a3 = 0.f, a4 = 0.f;
    float a5 = 0.f, a6 = 0.f, a7 = 0.f, a8 = 0.f, a9 = 0.f;
#pragma unroll 2
    for (int idx = beg; idx < end; ++idx) {
        int c = colP[idx];
        const float* wp = buf + (size_t)idx * 192;
        float w0 = wp[lane];
        float w1 = wp[64 + lane];
        float w2 = wp[128 + lane];
        const float* tp = Tn + (size_t)c * 640;
        a0 += w0 * tp[lane];
        a1 += w1 * tp[64 + lane];
        a2 += w1 * tp[128 + lane];
        a3 += w1 * tp[192 + lane];
        a4 += w2 * tp[256 + lane];
        a5 += w2 * tp[320 + lane];
        a6 += w2 * tp[384 + lane];
        a7 += w2 * tp[448 + lane];
        a8 += w2 * tp[512 + lane];
        a9 += w2 * tp[576 + lane];
    }
    float* mp = Mn + (size_t)n * 640;
    mp[lane] = a0;
    mp[64 + lane] = a1;  mp[128 + lane] = a2; mp[192 + lane] = a3;
    mp[256 + lane] = a4; mp[320 + lane] = a5; mp[384 + lane] = a6;
    mp[448 + lane] = a7; mp[512 + lane] = a8; mp[576 + lane] = a9;
}

// ---------------- node_post --------------------------------------------------
__global__ __launch_bounds__(64) void node_post(
    const float* __restrict__ X,
    const float* __restrict__ Tn, const float* __restrict__ Mn,
    const float* __restrict__ Wt3, const float* __restrict__ Wt4, const float* __restrict__ Wt5,
    float* __restrict__ out)
{
    int n = blockIdx.x, h = threadIdx.x;
    const float* Xb = X + (size_t)n * 9 * HD + h;
    float x[9];
    float nr = 0.f;
#pragma unroll
    for (int i = 0; i < 9; ++i) { x[i] = Xb[i * HD]; nr += x[i] * x[i]; }
    float xinv = 1.0f / (nr + 1.0f);
#pragma unroll
    for (int i = 0; i < 9; ++i) x[i] *= xinv;

    const float* tp = Tn + (size_t)n * 640 + h;
    const float* mp = Mn + (size_t)n * 640 + h;
    float yI = tp[0], mI = mp[0];
    float yA[3], yS[6], mA[3], mS[6];
#pragma unroll
    for (int j = 0; j < 3; ++j) { yA[j] = tp[(1 + j) * 64]; mA[j] = mp[(1 + j) * 64]; }
#pragma unroll
    for (int j = 0; j < 6; ++j) { yS[j] = tp[(4 + j) * 64]; mS[j] = mp[(4 + j) * 64]; }

    float M[3][3] = {
        { mI + mS[0],     mA[0] + mS[1],   mA[1] + mS[2] },
        { -mA[0] + mS[1], mI + mS[3],      mA[2] + mS[4] },
        { -mA[1] + mS[2], -mA[2] + mS[4],  mI + mS[5] } };
    float Y[3][3] = {
        { yI + yS[0],     yA[0] + yS[1],   yA[1] + yS[2] },
        { -yA[0] + yS[1], yI + yS[3],      yA[2] + yS[4] },
        { -yA[1] + yS[2], -yA[2] + yS[4],  yI + yS[5] } };

    float Cm[3][3];
    float nrm = 0.f;
#pragma unroll
    for (int a = 0; a < 3; ++a) {
#pragma unroll
        for (int b = 0; b < 3; ++b) {
            float s = 0.f;
#pragma unroll
            for (int c = 0; c < 3; ++c) s += M[a][c] * Y[c][b] + Y[a][c] * M[c][b];
            Cm[a][b] = s;
            nrm += s * s;
        }
    }
    float inv = 1.0f / (nrm + 1.0f);
    float tr3 = (Cm[0][0] + Cm[1][1] + Cm[2][2]) * (1.0f / 3.0f);

    __shared__ float comp[10][HD];
    comp[0][h] = tr3 * inv;
    comp[1][h] = 0.5f * (Cm[0][1] - Cm[1][0]) * inv;
    comp[2][h] = 0.5f * (Cm[0][2] - Cm[2][0]) * inv;
    comp[3][h] = 0.5f * (Cm[1][2] - Cm[2][1]) * inv;
    comp[4][h] = (Cm[0][0] - tr3) * inv;
    comp[5][h] = 0.5f * (Cm[0][1] + Cm[1][0]) * inv;
    comp[6][h] = 0.5f * (Cm[0][2] + Cm[2][0]) * inv;
    comp[7][h] = (Cm[1][1] - tr3) * inv;
    comp[8][h] = 0.5f * (Cm[1][2] + Cm[2][1]) * inv;
    comp[9][h] = (Cm[2][2] - tr3) * inv;
    __syncthreads();

    float acc[10];
#pragma unroll
    for (int i = 0; i < 10; ++i) acc[i] = 0.f;
    for (int k = 0; k < HD; ++k) {
        float w3 = Wt3[k * HD + h];
        float w4 = Wt4[k * HD + h];
        float w5 = Wt5[k * HD + h];
        acc[0] += comp[0][k] * w3;
        acc[1] += comp[1][k] * w4;
        acc[2] += comp[2][k] * w4;
        acc[3] += comp[3][k] * w4;
#pragma unroll
        for (int j = 0; j < 6; ++j) acc[4 + j] += comp[4 + j][k] * w5;
    }
    float D[3][3] = {
        { acc[0] + acc[4],  acc[1] + acc[5],  acc[2] + acc[6] },
        { -acc[1] + acc[5], acc[0] + acc[7],  acc[3] + acc[8] },
        { -acc[2] + acc[6], -acc[3] + acc[8], acc[0] + acc[9] } };

    float* ob = out + (size_t)n * 9 * HD + h;
#pragma unroll
    for (int a = 0; a < 3; ++a) {
#pragma unroll
        for (int b = 0; b < 3; ++b) {
            float s = 0.f;
#pragma unroll
            for (int c = 0; c < 3; ++c) s += D[a][c] * D[c][b];
            ob[(a * 3 + b) * HD] = x[a * 3 + b] + D[a][b] + s;
        }
    }
}

// ---------------- launch ------------------------------------------------------
extern "C" void kernel_launch(void* const* d_in, const int* in_sizes, int n_in,
                              void* d_out, int out_size, void* d_ws, size_t ws_size,
                              hipStream_t stream)
{
    const float* X           = (const float*)d_in[0];
    const float* charges     = (const float*)d_in[1];
    const float* edge_weight = (const float*)d_in[2];
    const float* edge_attr   = (const float*)d_in[3];
    const int*   edge_index  = (const int*)d_in[4];
    const float* Ws1 = (const float*)d_in[5];
    const float* bs1 = (const float*)d_in[6];
    const float* Ws2 = (const float*)d_in[7];
    const float* bs2 = (const float*)d_in[8];
    const float* Ws3 = (const float*)d_in[9];
    const float* bs3 = (const float*)d_in[10];
    const float* Wt0 = (const float*)d_in[11];
    const float* Wt1 = (const float*)d_in[12];
    const float* Wt2 = (const float*)d_in[13];
    const float* Wt3 = (const float*)d_in[14];
    const float* Wt4 = (const float*)d_in[15];
    const float* Wt5 = (const float*)d_in[16];

    int N = in_sizes[0] / (9 * HD);
    int E = in_sizes[2];

    float* ws = (float*)d_ws;
    float* Tn  = ws;                              // N*640
    float* Mn  = Tn + (size_t)N * 640;            // N*640
    float* buf = Mn + (size_t)N * 640;            // E*192 (CSR-permuted rows)
    float* cvP = buf + (size_t)E * 192;           // E (CSR-permuted)
    int* cnt   = (int*)(cvP + E);                 // N
    int* offs  = cnt + N;                         // N+1
    int* curs  = offs + N + 1;                    // N
    int* rank  = curs + N;                        // E
    int* colP  = rank + E;                        // E

    hipMemsetAsync(cnt, 0, (size_t)N * sizeof(int), stream);

    int nbE256 = (E + 255) / 256;
    count_kernel<<<nbE256, 256, 0, stream>>>(edge_index, cnt, E);
    scan_kernel<<<1, 1024, 0, stream>>>(cnt, offs, curs, N);
    place_kernel<<<nbE256, 256, 0, stream>>>(edge_index, curs, rank, colP, E);

    node_pre<<<N, 64, 0, stream>>>(X, Wt0, Wt1, Wt2, Tn);

    int nbE64 = (E + 63) / 64;
    mlp_l12<<<nbE64, 256, 0, stream>>>(edge_attr, charges, edge_weight, edge_index,
                                       Ws1, bs1, Ws2, bs2, rank, buf, cvP, E);
    mlp_l3<<<nbE64, 192, 0, stream>>>(Ws3, bs3, cvP, buf, E);

    msg_kernel<<<N, 64, 0, stream>>>(buf, colP, offs, Tn, Mn);

    node_post<<<N, 64, 0, stream>>>(X, Tn, Mn, Wt3, Wt4, Wt5, (float*)d_out);
}

// Round 6
// 684.961 us; speedup vs baseline: 1.2253x; 1.2253x over previous
//
#include <hip/hip_runtime.h>
#include <math.h>

#define HD 64

__device__ __forceinline__ float silu_f(float x) {
    return x / (1.0f + __expf(-x));
}

// ---------------- node_pre: normalize, decompose, Wt0/1/2 -> Tn[n][10][64] --
__global__ __launch_bounds__(64) void node_pre(
    const float* __restrict__ X,
    const float* __restrict__ Wt0, const float* __restrict__ Wt1, const float* __restrict__ Wt2,
    float* __restrict__ Tn)
{
    int n = blockIdx.x;
    int h = threadIdx.x;
    const float* Xb = X + (size_t)n * 9 * HD + h;
    float x[9];
    float nrm = 0.f;
#pragma unroll
    for (int i = 0; i < 9; ++i) { x[i] = Xb[i * HD]; nrm += x[i] * x[i]; }
    float inv = 1.0f / (nrm + 1.0f);
#pragma unroll
    for (int i = 0; i < 9; ++i) x[i] *= inv;

    float I0 = (x[0] + x[4] + x[8]) * (1.0f / 3.0f);
    __shared__ float comp[10][HD];
    comp[0][h] = I0;
    comp[1][h] = 0.5f * (x[1] - x[3]);
    comp[2][h] = 0.5f * (x[2] - x[6]);
    comp[3][h] = 0.5f * (x[5] - x[7]);
    comp[4][h] = x[0] - I0;
    comp[5][h] = 0.5f * (x[1] + x[3]);
    comp[6][h] = 0.5f * (x[2] + x[6]);
    comp[7][h] = x[4] - I0;
    comp[8][h] = 0.5f * (x[5] + x[7]);
    comp[9][h] = x[8] - I0;
    __syncthreads();
    float acc[10];
#pragma unroll
    for (int i = 0; i < 10; ++i) acc[i] = 0.f;
    for (int k = 0; k < HD; ++k) {
        float w0 = Wt0[k * HD + h];
        float w1 = Wt1[k * HD + h];
        float w2 = Wt2[k * HD + h];
        acc[0] += comp[0][k] * w0;
        acc[1] += comp[1][k] * w1;
        acc[2] += comp[2][k] * w1;
        acc[3] += comp[3][k] * w1;
#pragma unroll
        for (int j = 0; j < 6; ++j) acc[4 + j] += comp[4 + j][k] * w2;
    }
    float* tp = Tn + (size_t)n * 640 + h;
#pragma unroll
    for (int i = 0; i < 10; ++i) tp[i * 64] = acc[i];
}

// ---------------- CSR build --------------------------------------------------
__global__ __launch_bounds__(256) void count_kernel(
    const int* __restrict__ edge_index, int* __restrict__ cnt, int E)
{
    int e = blockIdx.x * 256 + threadIdx.x;
    if (e < E) atomicAdd(&cnt[edge_index[e]], 1);
}

__global__ __launch_bounds__(1024) void scan_kernel(
    const int* __restrict__ cnt, int* __restrict__ offs, int* __restrict__ curs, int N)
{
    __shared__ int partials[16];
    __shared__ int base_s;
    int tid = threadIdx.x, wid = tid >> 6, lane = tid & 63;
    if (tid == 0) base_s = 0;
    __syncthreads();
    for (int start = 0; start < N; start += 1024) {
        int i = start + tid;
        int v = (i < N) ? cnt[i] : 0;
        int s = v;
#pragma unroll
        for (int d = 1; d < 64; d <<= 1) {
            int t = __shfl_up(s, d, 64);
            if (lane >= d) s += t;
        }
        if (lane == 63) partials[wid] = s;
        __syncthreads();
        if (tid == 0) {
            int run = base_s;
#pragma unroll
            for (int w = 0; w < 16; ++w) { int t = partials[w]; partials[w] = run; run += t; }
            base_s = run;
        }
        __syncthreads();
        int excl = partials[wid] + s - v;
        if (i < N) { offs[i] = excl; curs[i] = excl; }
        __syncthreads();
    }
    if (tid == 0) offs[N] = base_s;
}

__global__ __launch_bounds__(256) void place_kernel(
    const int* __restrict__ edge_index, int* __restrict__ curs,
    int* __restrict__ rank, int* __restrict__ colP, int E)
{
    int e = blockIdx.x * 256 + threadIdx.x;
    if (e < E) {
        int p = atomicAdd(&curs[edge_index[e]], 1);
        rank[e] = p;
        colP[p] = edge_index[E + e];
    }
}

// ---------------- MLP l1/l2 chunk helpers (C0 literal -> scalar weight loads)
template<int C0>
__device__ __forceinline__ void l1_chunk(
    const float* __restrict__ Ws1, const float* __restrict__ bs1,
    const float (*ins)[49], float (*h1s)[65], int lane)
{
    float a[32];
#pragma unroll
    for (int j = 0; j < 32; j += 4) {
        float4 b = *(const float4*)(bs1 + C0 + j);
        a[j] = b.x; a[j + 1] = b.y; a[j + 2] = b.z; a[j + 3] = b.w;
    }
    for (int k = 0; k < 48; ++k) {
        float xk = ins[lane][k];
#pragma unroll
        for (int j = 0; j < 32; j += 4) {
            float4 w = *(const float4*)(Ws1 + k * 64 + C0 + j);
            a[j]     += xk * w.x;
            a[j + 1] += xk * w.y;
            a[j + 2] += xk * w.z;
            a[j + 3] += xk * w.w;
        }
    }
#pragma unroll
    for (int j = 0; j < 32; ++j) h1s[lane][C0 + j] = silu_f(a[j]);
}

template<int C0>
__device__ __forceinline__ void l2_chunk(
    const float* __restrict__ Ws2, const float* __restrict__ bs2,
    const float (*h1s)[65], int lane, float* op, bool valid)
{
    float a[64];
#pragma unroll
    for (int j = 0; j < 64; j += 4) {
        float4 b = *(const float4*)(bs2 + C0 + j);
        a[j] = b.x; a[j + 1] = b.y; a[j + 2] = b.z; a[j + 3] = b.w;
    }
    for (int k = 0; k < 64; ++k) {
        float xk = h1s[lane][k];
#pragma unroll
        for (int j = 0; j < 64; j += 4) {
            float4 w = *(const float4*)(Ws2 + k * 128 + C0 + j);
            a[j]     += xk * w.x;
            a[j + 1] += xk * w.y;
            a[j + 2] += xk * w.z;
            a[j + 3] += xk * w.w;
        }
    }
    if (valid) {
#pragma unroll
        for (int j = 0; j < 64; j += 4) {
            float4 o;
            o.x = silu_f(a[j]);     o.y = silu_f(a[j + 1]);
            o.z = silu_f(a[j + 2]); o.w = silu_f(a[j + 3]);
            *(float4*)(op + C0 + j) = o;
        }
    }
}

// ---------------- MLP layers 1+2: 128 thr (2 waves), LDS activations ---------
// Wave wv handles output chunk wv (literal via template) -> weights stay
// scalar-loaded. h2 written to CSR-permuted row rank[e].
__global__ __launch_bounds__(128, 4) void mlp_l12(
    const float* __restrict__ edge_attr, const float* __restrict__ charges,
    const float* __restrict__ edge_weight, const int* __restrict__ edge_index,
    const float* __restrict__ Ws1, const float* __restrict__ bs1,
    const float* __restrict__ Ws2, const float* __restrict__ bs2,
    const int* __restrict__ rank,
    float* __restrict__ buf, float* __restrict__ cvP, int E)
{
    __shared__ float ins[64][49];
    __shared__ float h1s[64][65];
    __shared__ int rankS[64];
    int tid = threadIdx.x;
    int wv = tid >> 6, lane = tid & 63;
    int ebase = blockIdx.x * 64;

    // stage inputs: 64 edges x 12 float4
    for (int i = tid; i < 768; i += 128) {
        int e_l = i / 12, f = i % 12;
        int e = ebase + e_l;
        int ee = (e < E) ? e : (E - 1);
        float4 v;
        if (f < 8) {
            v = *(const float4*)(edge_attr + (size_t)ee * 32 + f * 4);
        } else if (f < 10) {
            int r = edge_index[ee];
            v = *(const float4*)(charges + (size_t)r * 8 + (f - 8) * 4);
        } else {
            int c = edge_index[E + ee];
            v = *(const float4*)(charges + (size_t)c * 8 + (f - 10) * 4);
        }
        ins[e_l][f * 4 + 0] = v.x; ins[e_l][f * 4 + 1] = v.y;
        ins[e_l][f * 4 + 2] = v.z; ins[e_l][f * 4 + 3] = v.w;
    }
    if (tid < 64) {
        int e = ebase + tid;
        bool valid = (e < E);
        int ee = valid ? e : (E - 1);
        int rk = valid ? rank[ee] : 0;
        rankS[tid] = rk;
        float wgt = edge_weight[ee];
        float cv = 0.5f * (__cosf(wgt * 0.6283185307179586f) + 1.0f);
        cv = (wgt < 5.0f) ? cv : 0.0f;
        if (valid) cvP[rk] = cv;
    }
    __syncthreads();

    if (wv == 0) l1_chunk<0>(Ws1, bs1, ins, h1s, lane);
    else         l1_chunk<32>(Ws1, bs1, ins, h1s, lane);
    __syncthreads();

    bool valid = (ebase + lane) < E;
    float* op = buf + (size_t)rankS[lane] * 192;
    if (wv == 0) l2_chunk<0>(Ws2, bs2, h1s, lane, op, valid);
    else         l2_chunk<64>(Ws2, bs2, h1s, lane, op, valid);
}

// ---------------- MLP layer 3 chunk (C0 literal -> scalar weight loads) ------
template<int C0>
__device__ __forceinline__ void l3_chunk(
    const float* __restrict__ Ws3, const float* __restrict__ bs3,
    const float (*h2s)[129], int lane, float cv, float* op, bool valid)
{
    float a[64];
#pragma unroll
    for (int j = 0; j < 64; j += 4) {
        float4 b = *(const float4*)(bs3 + C0 + j);
        a[j] = b.x; a[j + 1] = b.y; a[j + 2] = b.z; a[j + 3] = b.w;
    }
    for (int k = 0; k < 128; ++k) {
        float xk = h2s[lane][k];
#pragma unroll
        for (int j = 0; j < 64; j += 4) {
            float4 w = *(const float4*)(Ws3 + k * 192 + C0 + j);
            a[j]     += xk * w.x;
            a[j + 1] += xk * w.y;
            a[j + 2] += xk * w.z;
            a[j + 3] += xk * w.w;
        }
    }
    if (valid) {
#pragma unroll
        for (int j = 0; j < 64; j += 4) {
            float4 o;
            o.x = silu_f(a[j]) * cv;     o.y = silu_f(a[j + 1]) * cv;
            o.z = silu_f(a[j + 2]) * cv; o.w = silu_f(a[j + 3]) * cv;
            *(float4*)(op + C0 + j) = o;
        }
    }
}

// ---------------- MLP layer 3: 192 thr (3 waves), h2 staged once in LDS ------
__global__ __launch_bounds__(192, 4) void mlp_l3(
    const float* __restrict__ Ws3, const float* __restrict__ bs3,
    const float* __restrict__ cvP, float* __restrict__ buf, int E)
{
    __shared__ float h2s[64][129];
    int tid = threadIdx.x;
    int base = blockIdx.x * 64;

    // stage 64 rows x 128 floats; r = lane-major -> conflict-free LDS writes
    for (int i = tid; i < 2048; i += 192) {
        int r = i & 63, c4 = (i >> 6) << 2;
        int p = base + r;
        float4 v = make_float4(0.f, 0.f, 0.f, 0.f);
        if (p < E) v = *(const float4*)(buf + (size_t)p * 192 + c4);
        h2s[r][c4] = v.x; h2s[r][c4 + 1] = v.y; h2s[r][c4 + 2] = v.z; h2s[r][c4 + 3] = v.w;
    }
    __syncthreads();

    int wv = tid >> 6, lane = tid & 63;
    int p = base + lane;
    bool valid = (p < E);
    float cv = valid ? cvP[p] : 0.f;
    float* op = buf + (size_t)p * 192;

    if (wv == 0)      l3_chunk<0>(Ws3, bs3, h2s, lane, cv, op, valid);
    else if (wv == 1) l3_chunk<64>(Ws3, bs3, h2s, lane, cv, op, valid);
    else              l3_chunk<128>(Ws3, bs3, h2s, lane, cv, op, valid);
}

// ---------------- msg kernel: sequential w stream + Tn gather ----------------
__global__ __launch_bounds__(64) void msg_kernel(
    const float* __restrict__ buf, const int* __restrict__ colP,
    const int* __restrict__ offs, const float* __restrict__ Tn,
    float* __restrict__ Mn)
{
    int n = blockIdx.x;
    int lane = threadIdx.x;
    int beg = offs[n], end = offs[n + 1];
    float a0 = 0.f, a1 = 0.f, a2 = 0.f, a3 = 0.f, a4 = 0.f;
    float a5 = 0.f, a6 = 0.f, a7 = 0.f, a8 = 0.f, a9 = 0.f;
#pragma unroll 2
    for (int idx = beg; idx < end; ++idx) {
        int c = colP[idx];
        const float* wp = buf + (size_t)idx * 192;
        float w0 = wp[lane];
        float w1 = wp[64 + lane];
        float w2 = wp[128 + lane];
        const float* tp = Tn + (size_t)c * 640;
        a0 += w0 * tp[lane];
        a1 += w1 * tp[64 + lane];
        a2 += w1 * tp[128 + lane];
        a3 += w1 * tp[192 + lane];
        a4 += w2 * tp[256 + lane];
        a5 += w2 * tp[320 + lane];
        a6 += w2 * tp[384 + lane];
        a7 += w2 * tp[448 + lane];
        a8 += w2 * tp[512 + lane];
        a9 += w2 * tp[576 + lane];
    }
    float* mp = Mn + (size_t)n * 640;
    mp[lane] = a0;
    mp[64 + lane] = a1;  mp[128 + lane] = a2; mp[192 + lane] = a3;
    mp[256 + lane] = a4; mp[320 + lane] = a5; mp[384 + lane] = a6;
    mp[448 + lane] = a7; mp[512 + lane] = a8; mp[576 + lane] = a9;
}

// ---------------- node_post --------------------------------------------------
__global__ __launch_bounds__(64) void node_post(
    const float* __restrict__ X,
    const float* __restrict__ Tn, const float* __restrict__ Mn,
    const float* __restrict__ Wt3, const float* __restrict__ Wt4, const float* __restrict__ Wt5,
    float* __restrict__ out)
{
    int n = blockIdx.x, h = threadIdx.x;
    const float* Xb = X + (size_t)n * 9 * HD + h;
    float x[9];
    float nr = 0.f;
#pragma unroll
    for (int i = 0; i < 9; ++i) { x[i] = Xb[i * HD]; nr += x[i] * x[i]; }
    float xinv = 1.0f / (nr + 1.0f);
#pragma unroll
    for (int i = 0; i < 9; ++i) x[i] *= xinv;

    const float* tp = Tn + (size_t)n * 640 + h;
    const float* mp = Mn + (size_t)n * 640 + h;
    float yI = tp[0], mI = mp[0];
    float yA[3], yS[6], mA[3], mS[6];
#pragma unroll
    for (int j = 0; j < 3; ++j) { yA[j] = tp[(1 + j) * 64]; mA[j] = mp[(1 + j) * 64]; }
#pragma unroll
    for (int j = 0; j < 6; ++j) { yS[j] = tp[(4 + j) * 64]; mS[j] = mp[(4 + j) * 64]; }

    float M[3][3] = {
        { mI + mS[0],     mA[0] + mS[1],   mA[1] + mS[2] },
        { -mA[0] + mS[1], mI + mS[3],      mA[2] + mS[4] },
        { -mA[1] + mS[2], -mA[2] + mS[4],  mI + mS[5] } };
    float Y[3][3] = {
        { yI + yS[0],     yA[0] + yS[1],   yA[1] + yS[2] },
        { -yA[0] + yS[1], yI + yS[3],      yA[2] + yS[4] },
        { -yA[1] + yS[2], -yA[2] + yS[4],  yI + yS[5] } };

    float Cm[3][3];
    float nrm = 0.f;
#pragma unroll
    for (int a = 0; a < 3; ++a) {
#pragma unroll
        for (int b = 0; b < 3; ++b) {
            float s = 0.f;
#pragma unroll
            for (int c = 0; c < 3; ++c) s += M[a][c] * Y[c][b] + Y[a][c] * M[c][b];
            Cm[a][b] = s;
            nrm += s * s;
        }
    }
    float inv = 1.0f / (nrm + 1.0f);
    float tr3 = (Cm[0][0] + Cm[1][1] + Cm[2][2]) * (1.0f / 3.0f);

    __shared__ float comp[10][HD];
    comp[0][h] = tr3 * inv;
    comp[1][h] = 0.5f * (Cm[0][1] - Cm[1][0]) * inv;
    comp[2][h] = 0.5f * (Cm[0][2] - Cm[2][0]) * inv;
    comp[3][h] = 0.5f * (Cm[1][2] - Cm[2][1]) * inv;
    comp[4][h] = (Cm[0][0] - tr3) * inv;
    comp[5][h] = 0.5f * (Cm[0][1] + Cm[1][0]) * inv;
    comp[6][h] = 0.5f * (Cm[0][2] + Cm[2][0]) * inv;
    comp[7][h] = (Cm[1][1] - tr3) * inv;
    comp[8][h] = 0.5f * (Cm[1][2] + Cm[2][1]) * inv;
    comp[9][h] = (Cm[2][2] - tr3) * inv;
    __syncthreads();

    float acc[10];
#pragma unroll
    for (int i = 0; i < 10; ++i) acc[i] = 0.f;
    for (int k = 0; k < HD; ++k) {
        float w3 = Wt3[k * HD + h];
        float w4 = Wt4[k * HD + h];
        float w5 = Wt5[k * HD + h];
        acc[0] += comp[0][k] * w3;
        acc[1] += comp[1][k] * w4;
        acc[2] += comp[2][k] * w4;
        acc[3] += comp[3][k] * w4;
#pragma unroll
        for (int j = 0; j < 6; ++j) acc[4 + j] += comp[4 + j][k] * w5;
    }
    float D[3][3] = {
        { acc[0] + acc[4],  acc[1] + acc[5],  acc[2] + acc[6] },
        { -acc[1] + acc[5], acc[0] + acc[7],  acc[3] + acc[8] },
        { -acc[2] + acc[6], -acc[3] + acc[8], acc[0] + acc[9] } };

    float* ob = out + (size_t)n * 9 * HD + h;
#pragma unroll
    for (int a = 0; a < 3; ++a) {
#pragma unroll
        for (int b = 0; b < 3; ++b) {
            float s = 0.f;
#pragma unroll
            for (int c = 0; c < 3; ++c) s += D[a][c] * D[c][b];
            ob[(a * 3 + b) * HD] = x[a * 3 + b] + D[a][b] + s;
        }
    }
}

// ---------------- launch ------------------------------------------------------
extern "C" void kernel_launch(void* const* d_in, const int* in_sizes, int n_in,
                              void* d_out, int out_size, void* d_ws, size_t ws_size,
                              hipStream_t stream)
{
    const float* X           = (const float*)d_in[0];
    const float* charges     = (const float*)d_in[1];
    const float* edge_weight = (const float*)d_in[2];
    const float* edge_attr   = (const float*)d_in[3];
    const int*   edge_index  = (const int*)d_in[4];
    const float* Ws1 = (const float*)d_in[5];
    const float* bs1 = (const float*)d_in[6];
    const float* Ws2 = (const float*)d_in[7];
    const float* bs2 = (const float*)d_in[8];
    const float* Ws3 = (const float*)d_in[9];
    const float* bs3 = (const float*)d_in[10];
    const float* Wt0 = (const float*)d_in[11];
    const float* Wt1 = (const float*)d_in[12];
    const float* Wt2 = (const float*)d_in[13];
    const float* Wt3 = (const float*)d_in[14];
    const float* Wt4 = (const float*)d_in[15];
    const float* Wt5 = (const float*)d_in[16];

    int N = in_sizes[0] / (9 * HD);
    int E = in_sizes[2];

    float* ws = (float*)d_ws;
    float* Tn  = ws;                              // N*640
    float* Mn  = Tn + (size_t)N * 640;            // N*640
    float* buf = Mn + (size_t)N * 640;            // E*192 (CSR-permuted rows)
    float* cvP = buf + (size_t)E * 192;           // E (CSR-permuted)
    int* cnt   = (int*)(cvP + E);                 // N
    int* offs  = cnt + N;                         // N+1
    int* curs  = offs + N + 1;                    // N
    int* rank  = curs + N;                        // E
    int* colP  = rank + E;                        // E

    hipMemsetAsync(cnt, 0, (size_t)N * sizeof(int), stream);

    int nbE256 = (E + 255) / 256;
    count_kernel<<<nbE256, 256, 0, stream>>>(edge_index, cnt, E);
    scan_kernel<<<1, 1024, 0, stream>>>(cnt, offs, curs, N);
    place_kernel<<<nbE256, 256, 0, stream>>>(edge_index, curs, rank, colP, E);

    node_pre<<<N, 64, 0, stream>>>(X, Wt0, Wt1, Wt2, Tn);

    int nbE64 = (E + 63) / 64;
    mlp_l12<<<nbE64, 128, 0, stream>>>(edge_attr, charges, edge_weight, edge_index,
                                       Ws1, bs1, Ws2, bs2, rank, buf, cvP, E);
    mlp_l3<<<nbE64, 192, 0, stream>>>(Ws3, bs3, cvP, buf, E);

    msg_kernel<<<N, 64, 0, stream>>>(buf, colP, offs, Tn, Mn);

    node_post<<<N, 64, 0, stream>>>(X, Tn, Mn, Wt3, Wt4, Wt5, (float*)d_out);
}